// Round 2
// baseline (488.363 us; speedup 1.0000x reference)
//
#include <hip/hip_runtime.h>
#include <hip/hip_bf16.h>
#include <hip/hip_fp16.h>

typedef _Float16 f16;
typedef _Float16 half8 __attribute__((ext_vector_type(8)));
typedef _Float16 half4 __attribute__((ext_vector_type(4)));
typedef float f32x4 __attribute__((ext_vector_type(4)));

#define BM 128
#define BN 128
#define BK 32

__device__ __forceinline__ float gelu_f(float x) {
  return 0.5f * x * (1.0f + erff(x * 0.70710678118654752f));
}

__device__ __forceinline__ void gll16(const void* g, void* l) {
  __builtin_amdgcn_global_load_lds((const __attribute__((address_space(1))) void*)g,
                                   (__attribute__((address_space(3))) void*)l,
                                   16, 0, 0);
}

// D[M][N] = act( P[M][K] * Q[N][K]^T + bias ), both P,Q fp16 K-inner.
// BIAS: 0 none, 1 by row, 2 by col, 3 rank-1 bias[row]*bias2[b*N+col].
// KSPLIT: write f32 partial at Dv + z*M*N.
// Double-buffered: stage tile t+1 while computing tile t (latency-bound regime).
template<int BIAS, bool GELU_ACT, bool OUT_F16, bool KSPLIT>
__global__ __launch_bounds__(256)
void gemm_tn(const f16* __restrict__ P, size_t sP, int ldP,
             const f16* __restrict__ Q, size_t sQ, int ldQ,
             void* __restrict__ Dv, size_t sD, int ldD,
             const float* __restrict__ bias, const float* __restrict__ bias2,
             int M, int N, int K, int nks)
{
  __shared__ __align__(16) char lds[32768];   // A0|A1|B0|B1, 8KB each

  const int t = threadIdx.x;
  const int l = t & 63;
  const int wid = t >> 6;
  const int wr = wid >> 1;
  const int wc = wid & 1;

  const int z = blockIdx.z;
  const int b = z / nks;
  const int s = z - b * nks;
  const int kLen = K / nks;
  const int k0 = s * kLen;

  const int mBase = blockIdx.y * BM;
  const int nBase = blockIdx.x * BN;

  const f16* Pb = P + (size_t)b * sP;
  const f16* Qb = Q + (size_t)b * sQ;

  // Staging geometry. XOR swizzle: physical 16B-chunk pc holds logical chunk
  // pc ^ ((row>>1)&3); applied on the GLOBAL source here and on ds_read below
  // (both-sides rule). LDS dest is linear (wave-uniform base + lane*16).
  const f16* srcA[2];
  const f16* srcB[2];
  int dstOff[2];
#pragma unroll
  for (int c = 0; c < 2; ++c) {
    const int off = c * 4096 + wid * 1024 + l * 16;
    const int row = off >> 6;
    const int gch = ((off >> 4) & 3) ^ ((row >> 1) & 3);
    srcA[c] = Pb + (size_t)(mBase + row) * ldP + k0 + gch * 8;
    srcB[c] = Qb + (size_t)(nBase + row) * ldQ + k0 + gch * 8;
    dstOff[c] = c * 4096 + wid * 1024;
  }

  f32x4 acc[4][4];
#pragma unroll
  for (int i = 0; i < 4; ++i)
#pragma unroll
    for (int j = 0; j < 4; ++j)
      acc[i][j] = (f32x4){0.f, 0.f, 0.f, 0.f};

  auto stage = [&](int buf) {
#pragma unroll
    for (int c = 0; c < 2; ++c) {
      gll16(srcA[c], lds + buf * 8192 + dstOff[c]);
      gll16(srcB[c], lds + 16384 + buf * 8192 + dstOff[c]);
      srcA[c] += BK;
      srcB[c] += BK;
    }
  };

  auto compute = [&](int buf) {
    half8 af[4], bf[4];
#pragma unroll
    for (int mi = 0; mi < 4; ++mi) {
      const int row = wr * 64 + mi * 16 + (l & 15);
      const int phys = row * 64 + ((((l >> 4) ^ (row >> 1)) & 3) << 4);
      af[mi] = *(const half8*)(lds + buf * 8192 + phys);
    }
#pragma unroll
    for (int ni = 0; ni < 4; ++ni) {
      const int row = wc * 64 + ni * 16 + (l & 15);
      const int phys = row * 64 + ((((l >> 4) ^ (row >> 1)) & 3) << 4);
      bf[ni] = *(const half8*)(lds + 16384 + buf * 8192 + phys);
    }
#pragma unroll
    for (int mi = 0; mi < 4; ++mi)
#pragma unroll
      for (int ni = 0; ni < 4; ++ni)
        acc[mi][ni] = __builtin_amdgcn_mfma_f32_16x16x32_f16(af[mi], bf[ni], acc[mi][ni], 0, 0, 0);
  };

  const int nk = kLen / BK;
  stage(0);
  __syncthreads();            // implicit vmcnt(0): tile 0 landed
  int cur = 0;
  for (int kt = 0; kt < nk - 1; ++kt) {
    stage(cur ^ 1);           // prefetch next tile; latency hides under compute
    compute(cur);
    __syncthreads();          // drains vmcnt(0) -> next tile ready; LDS reuse safe
    cur ^= 1;
  }
  compute(cur);

  float* Dsplit = nullptr; f16* D16 = nullptr; float* D32 = nullptr;
  if (KSPLIT)       Dsplit = (float*)Dv + (size_t)z * (size_t)(M * N);
  else if (OUT_F16) D16    = (f16*)Dv + (size_t)b * sD;
  else              D32    = (float*)Dv + (size_t)b * sD;

#pragma unroll
  for (int mi = 0; mi < 4; ++mi) {
    const int rb = mBase + wr * 64 + mi * 16 + ((l >> 4) << 2);
#pragma unroll
    for (int ni = 0; ni < 4; ++ni) {
      const int col = nBase + wc * 64 + ni * 16 + (l & 15);
#pragma unroll
      for (int j = 0; j < 4; ++j) {
        float v = acc[mi][ni][j];
        const int rr = rb + j;
        if (BIAS == 1) v += bias[rr];
        if (BIAS == 2) v += bias[col];
        if (BIAS == 3) v += bias[rr] * bias2[(size_t)b * N + col];
        if (GELU_ACT) v = gelu_f(v);
        if (KSPLIT)       Dsplit[(size_t)rr * ldD + col] = v;
        else if (OUT_F16) D16[(size_t)rr * ldD + col] = (f16)v;
        else              D32[(size_t)rr * ldD + col] = v;
      }
    }
  }
}

// in: [b][256][4096] f32 -> out: [b][4096][256] fp16
__global__ __launch_bounds__(256)
void transpose_cvt(const float* __restrict__ in, f16* __restrict__ outp) {
  __shared__ float tile[32][33];
  const int b = blockIdx.z;
  const int c0 = blockIdx.y * 32;
  const int n0 = blockIdx.x * 32;
  const int tx = threadIdx.x & 31;
  const int ty = threadIdx.x >> 5;
  const float* ib = in + (size_t)b * (256 * 4096);
  f16* ob = outp + (size_t)b * (256 * 4096);
#pragma unroll
  for (int i = 0; i < 4; ++i)
    tile[ty + i * 8][tx] = ib[(size_t)(c0 + ty + i * 8) * 4096 + n0 + tx];
  __syncthreads();
#pragma unroll
  for (int i = 0; i < 4; ++i)
    ob[(size_t)(n0 + ty + i * 8) * 256 + c0 + tx] = (f16)tile[tx][ty + i * 8];
}

// vectorized f32 -> f16, same layout; n8 = n/8
__global__ __launch_bounds__(256)
void cvtf16(const float* __restrict__ in, f16* __restrict__ outp, int n8) {
  int i = blockIdx.x * 256 + threadIdx.x;
  if (i < n8) {
    float4 a = ((const float4*)in)[2 * i];
    float4 c = ((const float4*)in)[2 * i + 1];
    half8 h = {(f16)a.x, (f16)a.y, (f16)a.z, (f16)a.w,
               (f16)c.x, (f16)c.y, (f16)c.z, (f16)c.w};
    ((half8*)outp)[i] = h;
  }
}

// ksum[r] = sum_n kH[r][n], r in [0, 16*256); one wave per row
__global__ __launch_bounds__(256)
void ksum_k(const f16* __restrict__ kH, float* __restrict__ ks) {
  const int r = blockIdx.x * 4 + (threadIdx.x >> 6);
  const int l = threadIdx.x & 63;
  const half8* row = (const half8*)(kH + (size_t)r * 4096);
  float s = 0.f;
#pragma unroll
  for (int j = 0; j < 8; ++j) {
    half8 h = row[l + 64 * j];
#pragma unroll
    for (int e = 0; e < 8; ++e) s += (float)h[e];
  }
#pragma unroll
  for (int off = 32; off; off >>= 1) s += __shfl_xor(s, off);
  if (l == 0) ks[r] = s;
}

// m1T[b][d][e] f16 = sum_{z=0..7} part[b*8+z][d][e]; 4 elems/thread
__global__ __launch_bounds__(256)
void reduce8_k(const float* __restrict__ part, f16* __restrict__ m1T) {
  const int i = blockIdx.x * 256 + threadIdx.x;   // float4 index, [0, 16*16384)
  const int b = i >> 14;
  const int e4 = i & 16383;
  const float4* base = (const float4*)part + (size_t)b * 131072 + e4;
  float4 s = {0.f, 0.f, 0.f, 0.f};
#pragma unroll
  for (int zz = 0; zz < 8; ++zz) {
    float4 p = base[(size_t)zz * 16384];
    s.x += p.x; s.y += p.y; s.z += p.z; s.w += p.w;
  }
  half4 h = {(f16)s.x, (f16)s.y, (f16)s.z, (f16)s.w};
  ((half4*)m1T)[i] = h;
}

// softmax over last dim of qk f32 [16*256][256] -> p fp16
__global__ __launch_bounds__(256)
void softmax_row(const float* __restrict__ qk, f16* __restrict__ p) {
  const int r = blockIdx.x * 4 + (threadIdx.x >> 6);
  const int l = threadIdx.x & 63;
  const float* row = qk + (size_t)r * 256;
  float v[4];
#pragma unroll
  for (int j = 0; j < 4; ++j) v[j] = row[l + 64 * j];
  float m = fmaxf(fmaxf(v[0], v[1]), fmaxf(v[2], v[3]));
#pragma unroll
  for (int off = 32; off; off >>= 1) m = fmaxf(m, __shfl_xor(m, off));
  float e[4], sum = 0.f;
#pragma unroll
  for (int j = 0; j < 4; ++j) { e[j] = expf(v[j] - m); sum += e[j]; }
#pragma unroll
  for (int off = 32; off; off >>= 1) sum += __shfl_xor(sum, off);
  const float inv = 1.0f / sum;
  f16* pb = p + (size_t)r * 256;
#pragma unroll
  for (int j = 0; j < 4; ++j) pb[l + 64 * j] = (f16)(e[j] * inv);
}

extern "C" void kernel_launch(void* const* d_in, const int* in_sizes, int n_in,
                              void* d_out, int out_size, void* d_ws, size_t ws_size,
                              hipStream_t stream) {
  const float* x      = (const float*)d_in[0];
  const float* qin    = (const float*)d_in[1];
  const float* w_kvl  = (const float*)d_in[2];
  const float* b_kvl  = (const float*)d_in[3];
  const float* w_q    = (const float*)d_in[4];
  const float* b_q    = (const float*)d_in[5];
  const float* w_proj = (const float*)d_in[6];
  const float* b_proj = (const float*)d_in[7];
  float* out = (float*)d_out;
  char* ws = (char*)d_ws;

  if (ws_size < 202129408) return;

  // layout (regions reused once dead):
  f16*   xt    = (f16*)(ws + 0);            // [16][4096][256] x^T fp16; dead after v GEMM
  float* part  = (float*)(ws + 0);          // [128][256][256] f32 m1 partials (reuses xt)
  f16*   qin16 = (f16*)(ws + 33554432);     // [16][256][4096] fp16; dead after m1 GEMM
  f16*   m1T   = (f16*)(ws + 33554432);     // [16][256][256] fp16 (reuses qin16)
  float* qkb   = (float*)(ws + 35651584);   // [16][256][256] f32
  f16*   pH    = (f16*)(ws + 39845888);     // [16][256][256] fp16
  f16*   wk16  = (f16*)(ws + 67108864);     // [768][256]
  f16*   wq16  = (f16*)(ws + 67502080);     // [256][256]
  f16*   wp16  = (f16*)(ws + 67633152);     // [256][512]
  float* ksum  = (float*)(ws + 67895296);   // [16][256]
  f16*   kH    = (f16*)(ws + 67911680);     // [16][256][4096]
  f16*   vt    = (f16*)(ws + 101466112);    // [16][4096][256]
  f16*   catT  = (f16*)(ws + 135020544);    // [16][4096][512]

  const size_t sAct = 1048576;
  dim3 blk(256);

  transpose_cvt<<<dim3(128, 8, 16), blk, 0, stream>>>(x, xt);
  cvtf16<<<dim3(8192), blk, 0, stream>>>(qin, qin16, 2097152);
  cvtf16<<<dim3(96),  blk, 0, stream>>>(w_kvl, wk16, 24576);
  cvtf16<<<dim3(32),  blk, 0, stream>>>(w_q, wq16, 8192);
  cvtf16<<<dim3(64),  blk, 0, stream>>>(w_proj, wp16, 16384);

  // k = gelu(Wkvl[256:512]·x + b): [d][n] -> kH
  hipLaunchKernelGGL((gemm_tn<1, true, true, false>), dim3(32, 2, 16), blk, 0, stream,
      wk16 + 65536, (size_t)0, 256, xt, sAct, 256,
      (void*)kH, sAct, 4096, b_kvl + 256, (const float*)nullptr, 256, 4096, 256, 1);
  // lfeat^T -> catT[:, 0:256]
  hipLaunchKernelGGL((gemm_tn<2, true, true, false>), dim3(2, 32, 16), blk, 0, stream,
      xt, sAct, 256, wk16, (size_t)0, 256,
      (void*)catT, (size_t)2097152, 512, b_kvl, (const float*)nullptr, 4096, 256, 256, 1);
  // v^T -> vt
  hipLaunchKernelGGL((gemm_tn<2, true, true, false>), dim3(2, 32, 16), blk, 0, stream,
      xt, sAct, 256, wk16 + 131072, (size_t)0, 256,
      (void*)vt, sAct, 256, b_kvl + 512, (const float*)nullptr, 4096, 256, 256, 1);

  // ksum[b][d] = sum_n k
  ksum_k<<<dim3(1024), blk, 0, stream>>>(kH, ksum);

  // m1T partials: [d][e] = sum_n kH[d][n]·qin16[e][n], split-K=8 over n
  hipLaunchKernelGGL((gemm_tn<0, false, false, true>), dim3(2, 2, 128), blk, 0, stream,
      kH, sAct, 4096, qin16, sAct, 4096,
      (void*)part, (size_t)0, 256, (const float*)nullptr, (const float*)nullptr, 256, 256, 4096, 8);
  reduce8_k<<<dim3(1024), blk, 0, stream>>>(part, m1T);

  // qk[c][d] = wq·m1T^T + b_q[c]*ksum[d]  (f32 out)
  hipLaunchKernelGGL((gemm_tn<3, false, false, false>), dim3(2, 2, 16), blk, 0, stream,
      wq16, (size_t)0, 256, m1T, (size_t)65536, 256,
      (void*)qkb, (size_t)65536, 256, b_q, ksum, 256, 256, 256, 1);

  softmax_row<<<dim3(1024), blk, 0, stream>>>(qkb, pH);

  // x2^T = v^T·p^T -> catT[:, 256:512]
  hipLaunchKernelGGL((gemm_tn<0, false, true, false>), dim3(2, 32, 16), blk, 0, stream,
      vt, sAct, 256, pH, (size_t)65536, 256,
      (void*)(catT + 256), (size_t)2097152, 512, (const float*)nullptr, (const float*)nullptr, 4096, 256, 256, 1);
  // out = gelu(Wproj·cat + b) f32
  hipLaunchKernelGGL((gemm_tn<1, true, false, false>), dim3(32, 2, 16), blk, 0, stream,
      wp16, (size_t)0, 512, catT, (size_t)2097152, 512,
      (void*)out, sAct, 4096, b_proj, (const float*)nullptr, 256, 4096, 512, 1);
}

// Round 3
// 383.901 us; speedup vs baseline: 1.2721x; 1.2721x over previous
//
#include <hip/hip_runtime.h>
#include <hip/hip_bf16.h>
#include <hip/hip_fp16.h>

typedef _Float16 f16;
typedef _Float16 half8 __attribute__((ext_vector_type(8)));
typedef _Float16 half4 __attribute__((ext_vector_type(4)));
typedef float f32x4 __attribute__((ext_vector_type(4)));

__device__ __forceinline__ float gelu_f(float x) {
  return 0.5f * x * (1.0f + erff(x * 0.70710678118654752f));
}

__device__ __forceinline__ void gll16(const void* g, void* l) {
  __builtin_amdgcn_global_load_lds((const __attribute__((address_space(1))) void*)g,
                                   (__attribute__((address_space(3))) void*)l,
                                   16, 0, 0);
}

// ---------------- Template-W: D[m<=256][n] = gelu(W[m][KK]·Act[n][KK]^T + bias[m])
// W per-wave in registers (loaded once per block). Act staged in full-K panels,
// 2-phase dbuf, counted vmcnt, raw barriers. 8 waves; wave owns 32 m-rows.
template<int KK, bool OUT_F16>
__global__ __launch_bounds__(512, 2)
void gemm_wstat(const f16* __restrict__ W, size_t sW,
                const f16* __restrict__ Act, size_t sA,
                void* __restrict__ Dv, size_t sD,
                const float* __restrict__ bias,
                int panelsPerBlock, int blocksPerBatch)
{
  constexpr int PN  = (KK == 512) ? 32 : 64;     // panel rows (n)
  constexpr int PB  = PN * KK * 2;               // 32 KB both
  constexpr int NKS = KK / 32;
  constexpr int NT  = PN / 16;
  __shared__ __align__(16) char lds[2 * PB];     // 64 KB

  const int t = threadIdx.x;
  const int l = t & 63;
  const int w = t >> 6;
  const int bid = blockIdx.x;
  const int b = bid / blocksPerBatch;
  const int blkInB = bid - b * blocksPerBatch;

  const f16* Wb = W + (size_t)b * sW;
  const f16* Ab = Act + (size_t)b * sA;

  // W frags: wave w owns m-rows [32w, 32w+32)
  half8 wf[2][NKS];
#pragma unroll
  for (int mt = 0; mt < 2; ++mt)
#pragma unroll
    for (int ks = 0; ks < NKS; ++ks) {
      const int row = w * 32 + mt * 16 + (l & 15);
      wf[mt][ks] = *(const half8*)(Wb + (size_t)row * KK + ks * 32 + (l >> 4) * 8);
    }

  // staging: linear LDS dest; source chunk pre-swizzled (chunk ^ (row&7))
  auto stage = [&](int buf, int p) {
    const int n0 = (blkInB * panelsPerBlock + p) * PN;
#pragma unroll
    for (int i = 0; i < 4; ++i) {
      const int off = (i * 8 + w) * 1024 + l * 16;
      const int row = off / (KK * 2);
      const int chunk = (off & (KK * 2 - 1)) >> 4;
      const int lch = chunk ^ (row & 7);
      gll16(Ab + (size_t)(n0 + row) * KK + lch * 8, lds + buf * PB + (i * 8 + w) * 1024);
    }
  };

  int buf = 0;
  stage(0, 0);
  for (int p = 0; p < panelsPerBlock; ++p) {
    if (p + 1 < panelsPerBlock) {
      stage(buf ^ 1, p + 1);
      asm volatile("s_waitcnt vmcnt(4)" ::: "memory");   // current panel landed; next in flight
    } else {
      asm volatile("s_waitcnt vmcnt(0)" ::: "memory");
    }
    asm volatile("s_barrier" ::: "memory");

    f32x4 acc[2][NT];
#pragma unroll
    for (int mt = 0; mt < 2; ++mt)
#pragma unroll
      for (int nt = 0; nt < NT; ++nt)
        acc[mt][nt] = (f32x4){0.f, 0.f, 0.f, 0.f};
#pragma unroll
    for (int ks = 0; ks < NKS; ++ks) {
      half8 bf[NT];
#pragma unroll
      for (int nt = 0; nt < NT; ++nt) {
        const int row = nt * 16 + (l & 15);
        const int ch = (ks * 4 + (l >> 4)) ^ (row & 7);
        bf[nt] = *(const half8*)(lds + buf * PB + row * (KK * 2) + ch * 16);
      }
#pragma unroll
      for (int mt = 0; mt < 2; ++mt)
#pragma unroll
        for (int nt = 0; nt < NT; ++nt)
          acc[mt][nt] = __builtin_amdgcn_mfma_f32_16x16x32_f16(wf[mt][ks], bf[nt], acc[mt][nt], 0, 0, 0);
    }

    const int n0 = (blkInB * panelsPerBlock + p) * PN;
#pragma unroll
    for (int mt = 0; mt < 2; ++mt) {
      const int rb = w * 32 + mt * 16 + ((l >> 4) << 2);
#pragma unroll
      for (int nt = 0; nt < NT; ++nt) {
        const int col = n0 + nt * 16 + (l & 15);
#pragma unroll
        for (int j = 0; j < 4; ++j) {
          const int rr = rb + j;
          float v = gelu_f(acc[mt][nt][j] + bias[rr]);
          if (OUT_F16) ((f16*)Dv + (size_t)b * sD)[(size_t)rr * 4096 + col] = (f16)v;
          else         ((float*)Dv + (size_t)b * sD)[(size_t)rr * 4096 + col] = v;
        }
      }
    }
    asm volatile("s_barrier" ::: "memory");   // all waves done reading buf before re-stage
    buf ^= 1;
  }
}

// ---------------- Template-S: D[n][512] = gelu(Act[n][256]·W[512][256]^T + b_kvl[colmap])
// W on the B-side in registers; streams Act panels. Wave owns 64 c-cols.
__global__ __launch_bounds__(512, 2)
void gemm_sstat(const f16* __restrict__ Act, size_t sA,
                const f16* __restrict__ W,
                f16* __restrict__ Dp, size_t sD,
                const float* __restrict__ bias,
                int panelsPerBlock, int blocksPerBatch)
{
  constexpr int KK = 256, PN = 64, PB = PN * KK * 2;   // 32 KB
  __shared__ __align__(16) char lds[2 * PB];

  const int t = threadIdx.x;
  const int l = t & 63;
  const int w = t >> 6;
  const int bid = blockIdx.x;
  const int b = bid / blocksPerBatch;
  const int blkInB = bid - b * blocksPerBatch;

  const f16* Ab = Act + (size_t)b * sA;

  half8 wf[4][8];                 // wave's 64 c-rows of W, full K=256
#pragma unroll
  for (int ct = 0; ct < 4; ++ct)
#pragma unroll
    for (int ks = 0; ks < 8; ++ks) {
      const int row = w * 64 + ct * 16 + (l & 15);
      wf[ct][ks] = *(const half8*)(W + (size_t)row * 256 + ks * 32 + (l >> 4) * 8);
    }

  auto stage = [&](int buf, int p) {
    const int n0 = (blkInB * panelsPerBlock + p) * PN;
#pragma unroll
    for (int i = 0; i < 4; ++i) {
      const int off = (i * 8 + w) * 1024 + l * 16;
      const int row = off >> 9;
      const int chunk = (off & 511) >> 4;
      const int lch = chunk ^ (row & 7);
      gll16(Ab + (size_t)(n0 + row) * 256 + lch * 8, lds + buf * PB + (i * 8 + w) * 1024);
    }
  };

  int buf = 0;
  stage(0, 0);
  for (int p = 0; p < panelsPerBlock; ++p) {
    if (p + 1 < panelsPerBlock) {
      stage(buf ^ 1, p + 1);
      asm volatile("s_waitcnt vmcnt(4)" ::: "memory");
    } else {
      asm volatile("s_waitcnt vmcnt(0)" ::: "memory");
    }
    asm volatile("s_barrier" ::: "memory");

    f32x4 acc[4][4];
#pragma unroll
    for (int nt = 0; nt < 4; ++nt)
#pragma unroll
      for (int ct = 0; ct < 4; ++ct)
        acc[nt][ct] = (f32x4){0.f, 0.f, 0.f, 0.f};
#pragma unroll
    for (int ks = 0; ks < 8; ++ks) {
      half8 af[4];
#pragma unroll
      for (int nt = 0; nt < 4; ++nt) {
        const int row = nt * 16 + (l & 15);
        const int ch = (ks * 4 + (l >> 4)) ^ (row & 7);
        af[nt] = *(const half8*)(lds + buf * PB + row * 512 + ch * 16);
      }
#pragma unroll
      for (int nt = 0; nt < 4; ++nt)
#pragma unroll
        for (int ct = 0; ct < 4; ++ct)
          acc[nt][ct] = __builtin_amdgcn_mfma_f32_16x16x32_f16(af[nt], wf[ct][ks], acc[nt][ct], 0, 0, 0);
    }

    const int n0 = (blkInB * panelsPerBlock + p) * PN;
    f16* Db = Dp + (size_t)b * sD;
#pragma unroll
    for (int nt = 0; nt < 4; ++nt) {
      const int rb = n0 + nt * 16 + ((l >> 4) << 2);
#pragma unroll
      for (int ct = 0; ct < 4; ++ct) {
        const int col = w * 64 + ct * 16 + (l & 15);
        const int bi = col + (col >= 256 ? 256 : 0);   // lfeat rows 0:256, v rows 512:768
        const float bv = bias[bi];
#pragma unroll
        for (int j = 0; j < 4; ++j)
          Db[(size_t)(rb + j) * 512 + col] = (f16)gelu_f(acc[nt][ct][j] + bv);
      }
    }
    asm volatile("s_barrier" ::: "memory");
    buf ^= 1;
  }
}

// ---------------- round-1 gemm_tn (single-buffer; proven) for m1 / qk / Wxp
#define BM 128
#define BN 128
#define BK 32
template<int BIAS, bool GELU_ACT, bool OUT_F16, bool KSPLIT>
__global__ __launch_bounds__(256)
void gemm_tn(const f16* __restrict__ P, size_t sP, int ldP,
             const f16* __restrict__ Q, size_t sQ, int ldQ,
             void* __restrict__ Dv, size_t sD, int ldD,
             const float* __restrict__ bias, const float* __restrict__ bias2,
             int M, int N, int K, int nks)
{
  __shared__ __align__(16) f16 ldsA[BM * BK];
  __shared__ __align__(16) f16 ldsB[BM * BK];

  const int t = threadIdx.x;
  const int l = t & 63;
  const int wid = t >> 6;
  const int wr = wid >> 1;
  const int wc = wid & 1;

  const int z = blockIdx.z;
  const int b = z / nks;
  const int s = z - b * nks;
  const int kLen = K / nks;
  const int k0 = s * kLen;

  const int mBase = blockIdx.y * BM;
  const int nBase = blockIdx.x * BN;

  const f16* Pb = P + (size_t)b * sP;
  const f16* Qb = Q + (size_t)b * sQ;

  f32x4 acc[4][4];
#pragma unroll
  for (int i = 0; i < 4; ++i)
#pragma unroll
    for (int j = 0; j < 4; ++j)
      acc[i][j] = (f32x4){0.f, 0.f, 0.f, 0.f};

  const int nk = kLen / BK;
  for (int kt = 0; kt < nk; ++kt) {
    const int kk = k0 + kt * BK;
#pragma unroll
    for (int c = 0; c < 2; ++c) {
      const int off = c * 4096 + wid * 1024 + l * 16;
      const int row = off >> 6;
      const int gch = ((off >> 4) & 3) ^ ((row >> 1) & 3);
      gll16(Pb + (size_t)(mBase + row) * ldP + kk + gch * 8,
            (char*)ldsA + c * 4096 + wid * 1024);
      gll16(Qb + (size_t)(nBase + row) * ldQ + kk + gch * 8,
            (char*)ldsB + c * 4096 + wid * 1024);
    }
    asm volatile("s_waitcnt vmcnt(0)" ::: "memory");
    __syncthreads();

    half8 af[4], bf[4];
#pragma unroll
    for (int mi = 0; mi < 4; ++mi) {
      const int row = wr * 64 + mi * 16 + (l & 15);
      const int phys = row * 64 + ((((l >> 4) ^ (row >> 1)) & 3) << 4);
      af[mi] = *(const half8*)((const char*)ldsA + phys);
    }
#pragma unroll
    for (int ni = 0; ni < 4; ++ni) {
      const int row = wc * 64 + ni * 16 + (l & 15);
      const int phys = row * 64 + ((((l >> 4) ^ (row >> 1)) & 3) << 4);
      bf[ni] = *(const half8*)((const char*)ldsB + phys);
    }
#pragma unroll
    for (int mi = 0; mi < 4; ++mi)
#pragma unroll
      for (int ni = 0; ni < 4; ++ni)
        acc[mi][ni] = __builtin_amdgcn_mfma_f32_16x16x32_f16(af[mi], bf[ni], acc[mi][ni], 0, 0, 0);
    __syncthreads();
  }

  float* Dsplit = nullptr; f16* D16 = nullptr; float* D32 = nullptr;
  if (KSPLIT)       Dsplit = (float*)Dv + (size_t)z * (size_t)(M * N);
  else if (OUT_F16) D16    = (f16*)Dv + (size_t)b * sD;
  else              D32    = (float*)Dv + (size_t)b * sD;

#pragma unroll
  for (int mi = 0; mi < 4; ++mi) {
    const int rb = mBase + wr * 64 + mi * 16 + ((l >> 4) << 2);
#pragma unroll
    for (int ni = 0; ni < 4; ++ni) {
      const int col = nBase + wc * 64 + ni * 16 + (l & 15);
#pragma unroll
      for (int j = 0; j < 4; ++j) {
        float v = acc[mi][ni][j];
        const int rr = rb + j;
        if (BIAS == 1) v += bias[rr];
        if (BIAS == 2) v += bias[col];
        if (BIAS == 3) v += bias[rr] * bias2[(size_t)b * N + col];
        if (GELU_ACT) v = gelu_f(v);
        if (KSPLIT)       Dsplit[(size_t)rr * ldD + col] = v;
        else if (OUT_F16) D16[(size_t)rr * ldD + col] = (f16)v;
        else              D32[(size_t)rr * ldD + col] = v;
      }
    }
  }
}

// ---------------- small kernels
// x [b][256][4096] f32 -> xt [b][4096][256] f16, 64x64 tiles, vectorized
__global__ __launch_bounds__(256)
void transpose64(const float* __restrict__ in, f16* __restrict__ outp) {
  __shared__ float tile[64][65];
  const int b = blockIdx.z, c0 = blockIdx.y * 64, n0 = blockIdx.x * 64;
  const int t = threadIdx.x;
  const float* ib = in + (size_t)b * 1048576;
  f16* ob = outp + (size_t)b * 1048576;
  const int cl = t >> 4, c4 = t & 15;
#pragma unroll
  for (int i = 0; i < 4; ++i) {
    float4 v = *(const float4*)(ib + (size_t)(c0 + cl + i * 16) * 4096 + n0 + c4 * 4);
    tile[cl + i * 16][c4 * 4 + 0] = v.x;
    tile[cl + i * 16][c4 * 4 + 1] = v.y;
    tile[cl + i * 16][c4 * 4 + 2] = v.z;
    tile[cl + i * 16][c4 * 4 + 3] = v.w;
  }
  __syncthreads();
  const int nl = t >> 3, ch = t & 7;
#pragma unroll
  for (int i = 0; i < 2; ++i) {
    const int n = nl + i * 32;
    half8 h;
#pragma unroll
    for (int e = 0; e < 8; ++e) h[e] = (f16)tile[ch * 8 + e][n];
    *(half8*)(ob + (size_t)(n0 + n) * 256 + c0 + ch * 8) = h;
  }
}

__global__ __launch_bounds__(256)
void cvtf16(const float* __restrict__ in, f16* __restrict__ outp, int n8) {
  int i = blockIdx.x * 256 + threadIdx.x;
  if (i < n8) {
    float4 a = ((const float4*)in)[2 * i];
    float4 c = ((const float4*)in)[2 * i + 1];
    half8 h = {(f16)a.x, (f16)a.y, (f16)a.z, (f16)a.w,
               (f16)c.x, (f16)c.y, (f16)c.z, (f16)c.w};
    ((half8*)outp)[i] = h;
  }
}

// split w_proj [256][512]: Wx16[o][c]=wp[o][256+c]; Wcat[b][o][c]=wp[o][c] for all b
__global__ __launch_bounds__(256)
void wsplit(const float* __restrict__ wp, f16* __restrict__ Wx, f16* __restrict__ Wcat) {
  const int o = blockIdx.x, c = threadIdx.x;
  const f16 lf = (f16)wp[o * 512 + c];
  Wx[o * 256 + c] = (f16)wp[o * 512 + 256 + c];
#pragma unroll
  for (int b = 0; b < 16; ++b) Wcat[(size_t)b * 131072 + o * 512 + c] = lf;
}

__global__ __launch_bounds__(256)
void ksum_k(const f16* __restrict__ kH, float* __restrict__ ks) {
  const int r = blockIdx.x * 4 + (threadIdx.x >> 6);
  const int l = threadIdx.x & 63;
  const half8* row = (const half8*)(kH + (size_t)r * 4096);
  float s = 0.f;
#pragma unroll
  for (int j = 0; j < 8; ++j) {
    half8 h = row[l + 64 * j];
#pragma unroll
    for (int e = 0; e < 8; ++e) s += (float)h[e];
  }
#pragma unroll
  for (int off = 32; off; off >>= 1) s += __shfl_xor(s, off);
  if (l == 0) ks[r] = s;
}

__global__ __launch_bounds__(256)
void reduce8_k(const float* __restrict__ part, f16* __restrict__ m1T) {
  const int i = blockIdx.x * 256 + threadIdx.x;
  const int b = i >> 14;
  const int e4 = i & 16383;
  const float4* base = (const float4*)part + (size_t)b * 131072 + e4;
  float4 s = {0.f, 0.f, 0.f, 0.f};
#pragma unroll
  for (int zz = 0; zz < 8; ++zz) {
    float4 p = base[(size_t)zz * 16384];
    s.x += p.x; s.y += p.y; s.z += p.z; s.w += p.w;
  }
  half4 h = {(f16)s.x, (f16)s.y, (f16)s.z, (f16)s.w};
  ((half4*)m1T)[i] = h;
}

// row-softmax of qk [16][256][256] f32 over last axis; write TRANSPOSED pT[d][c] f16
__global__ __launch_bounds__(256)
void softmaxT(const float* __restrict__ qk, f16* __restrict__ pT) {
  __shared__ f16 sm[4][256];
  const int wid = threadIdx.x >> 6, l = threadIdx.x & 63;
  const int b = blockIdx.y;
  const int c = blockIdx.x * 4 + wid;
  const float* row = qk + ((size_t)b * 256 + c) * 256;
  float v[4];
#pragma unroll
  for (int j = 0; j < 4; ++j) v[j] = row[l + 64 * j];
  float m = fmaxf(fmaxf(v[0], v[1]), fmaxf(v[2], v[3]));
#pragma unroll
  for (int off = 32; off; off >>= 1) m = fmaxf(m, __shfl_xor(m, off));
  float e[4], sum = 0.f;
#pragma unroll
  for (int j = 0; j < 4; ++j) { e[j] = expf(v[j] - m); sum += e[j]; }
#pragma unroll
  for (int off = 32; off; off >>= 1) sum += __shfl_xor(sum, off);
  const float inv = 1.0f / sum;
#pragma unroll
  for (int j = 0; j < 4; ++j) sm[wid][l + 64 * j] = (f16)(e[j] * inv);
  __syncthreads();
  const int d = threadIdx.x;
  half4 h = {sm[0][d], sm[1][d], sm[2][d], sm[3][d]};
  *(half4*)(pT + ((size_t)b * 256 + d) * 256 + blockIdx.x * 4) = h;
}

extern "C" void kernel_launch(void* const* d_in, const int* in_sizes, int n_in,
                              void* d_out, int out_size, void* d_ws, size_t ws_size,
                              hipStream_t stream) {
  const float* x      = (const float*)d_in[0];
  const float* qin    = (const float*)d_in[1];
  const float* w_kvl  = (const float*)d_in[2];
  const float* b_kvl  = (const float*)d_in[3];
  const float* w_q    = (const float*)d_in[4];
  const float* b_q    = (const float*)d_in[5];
  const float* w_proj = (const float*)d_in[6];
  const float* b_proj = (const float*)d_in[7];
  float* out = (float*)d_out;
  char* ws = (char*)d_ws;

  if (ws_size < 182000000) return;

  f16*   xt    = (f16*)(ws + 0);            // [16][4096][256]; reused as part later
  float* part  = (float*)(ws + 0);          // [128][256][256] f32
  f16*   qin16 = (f16*)(ws + 33554432);     // [16][256][4096]
  f16*   kH    = (f16*)(ws + 67108864);     // [16][256][4096]
  f16*   lvT   = (f16*)(ws + 100663296);    // [16][4096][512]
  f16*   wk_lv = (f16*)(ws + 167772160);    // [512][256] = [wk0 ; wk2]
  f16*   wkK   = (f16*)(ws + 168034304);    // [256][256]
  f16*   wq16  = (f16*)(ws + 168165376);    // [256][256]
  f16*   Wx16  = (f16*)(ws + 168296448);    // [256][256]
  f16*   Wcat  = (f16*)(ws + 168427520);    // [16][256][512]
  float* ksum  = (float*)(ws + 172621824);  // [16][256]
  f16*   m1T   = (f16*)(ws + 172638208);    // [16][256][256]
  float* qkb   = (float*)(ws + 174735360);  // [16][256][256]
  f16*   pT    = (f16*)(ws + 178929664);    // [16][256][256]

  const size_t sAct = 1048576;
  dim3 blk(256), blk512(512);

  transpose64<<<dim3(64, 4, 16), blk, 0, stream>>>(x, xt);
  cvtf16<<<dim3(8192), blk, 0, stream>>>(qin, qin16, 2097152);
  cvtf16<<<dim3(32), blk, 0, stream>>>(w_kvl, wk_lv, 8192);                 // lfeat rows
  cvtf16<<<dim3(32), blk, 0, stream>>>(w_kvl + 131072, wk_lv + 65536, 8192); // v rows
  cvtf16<<<dim3(32), blk, 0, stream>>>(w_kvl + 65536, wkK, 8192);            // k rows
  cvtf16<<<dim3(32), blk, 0, stream>>>(w_q, wq16, 8192);
  wsplit<<<dim3(256), blk, 0, stream>>>(w_proj, Wx16, Wcat);

  // kH[d][n] = gelu(wkK·x + b)
  hipLaunchKernelGGL((gemm_wstat<256, true>), dim3(512), blk512, 0, stream,
      wkK, (size_t)0, xt, sAct, (void*)kH, sAct, b_kvl + 256, 2, 32);
  // lvT[n][512] = gelu(x^T·wk_lv^T + b)
  gemm_sstat<<<dim3(512), blk512, 0, stream>>>(xt, sAct, wk_lv, lvT, (size_t)2097152, b_kvl, 2, 32);

  ksum_k<<<dim3(1024), blk, 0, stream>>>(kH, ksum);

  // M1[d][e] partials (split-K over n), then reduce -> m1T f16
  hipLaunchKernelGGL((gemm_tn<0, false, false, true>), dim3(2, 2, 128), blk, 0, stream,
      kH, sAct, 4096, qin16, sAct, 4096,
      (void*)part, (size_t)0, 256, (const float*)nullptr, (const float*)nullptr, 256, 256, 4096, 8);
  reduce8_k<<<dim3(1024), blk, 0, stream>>>(part, m1T);

  // qk[c][d] = wq·M1^T + b_q[c]*ksum[d]
  hipLaunchKernelGGL((gemm_tn<3, false, false, false>), dim3(2, 2, 16), blk, 0, stream,
      wq16, (size_t)0, 256, m1T, (size_t)65536, 256,
      (void*)qkb, (size_t)65536, 256, b_q, ksum, 256, 256, 256, 1);

  softmaxT<<<dim3(64, 16), blk, 0, stream>>>(qkb, pT);

  // Wxp[o][d] = Wx·p -> Wcat[:, 256:512]
  hipLaunchKernelGGL((gemm_tn<0, false, true, false>), dim3(2, 2, 16), blk, 0, stream,
      Wx16, (size_t)0, 256, pT, (size_t)65536, 256,
      (void*)(Wcat + 256), (size_t)131072, 512, (const float*)nullptr, (const float*)nullptr, 256, 256, 256, 1);

  // out[o][n] = gelu(Wcat_b·lvT^T + b_proj) f32
  hipLaunchKernelGGL((gemm_wstat<512, false>), dim3(512), blk512, 0, stream,
      Wcat, (size_t)131072, lvT, (size_t)2097152, (void*)out, sAct, b_proj, 4, 32);
}